// Round 5
// baseline (661.288 us; speedup 1.0000x reference)
//
#include <hip/hip_runtime.h>

// ---------------------------------------------------------------------------
// GQ sliding-window attention, MI355X (gfx950).
// Pipeline: cast(bf16) -> fused QKV GEMM (MFMA) -> trig table ->
//           banded GQA attention (MFMA, swapped-QK^T + LDS-transposed V) ->
//           output GEMM (MFMA) -> fp32 out.
// Round 4: resubmission (GPU unavailable rounds 0,1,3,4; compile-fix in r2
// has never executed). Fragment layouts + P-exchange independently
// re-derived this round; no source change.
// ---------------------------------------------------------------------------

typedef __attribute__((ext_vector_type(8))) __bf16 bf16x8;
typedef __attribute__((ext_vector_type(4))) float f32x4;
typedef __attribute__((ext_vector_type(8))) unsigned short u16x8;
typedef __attribute__((ext_vector_type(4))) unsigned short u16x4;
typedef __attribute__((ext_vector_type(4))) unsigned int u32x4;

#define DIM_   2048
#define TLEN   4096
#define NH_    16
#define NKV_   4
#define HD_    128
#define QKVN   3072   // 2048 q + 512 k + 512 v
#define GK     2048   // GEMM K dim

__device__ __forceinline__ unsigned short f2bf(float f) {
  unsigned u = __builtin_bit_cast(unsigned, f);
  u += 0x7fffu + ((u >> 16) & 1u);
  return (unsigned short)(u >> 16);
}
__device__ __forceinline__ float bf2f(unsigned short h) {
  unsigned u = ((unsigned)h) << 16;
  return __builtin_bit_cast(float, u);
}
__device__ __forceinline__ void gll16(const void* g, void* l) {
  __builtin_amdgcn_global_load_lds(
      (const __attribute__((address_space(1))) unsigned int*)g,
      (__attribute__((address_space(3))) unsigned int*)l, 16, 0, 0);
}
// row-dependent XOR swizzle: spreads 16B slots across banks for both the
// (row-varies, col-fixed) fragment reads and the staging writes.
__device__ __forceinline__ int swzr(int row) { return ((row ^ (row >> 3)) & 7) << 4; }

// ---------------- cast kernels ----------------
__global__ void cast_f32_bf16_k(const float* __restrict__ src,
                                unsigned short* __restrict__ dst, int n8) {
  int stride = gridDim.x * blockDim.x;
  for (int i = blockIdx.x * blockDim.x + threadIdx.x; i < n8; i += stride) {
    f32x4 a = ((const f32x4*)src)[2 * i];
    f32x4 b = ((const f32x4*)src)[2 * i + 1];
    u16x8 o;
    o[0] = f2bf(a[0]); o[1] = f2bf(a[1]); o[2] = f2bf(a[2]); o[3] = f2bf(a[3]);
    o[4] = f2bf(b[0]); o[5] = f2bf(b[1]); o[6] = f2bf(b[2]); o[7] = f2bf(b[3]);
    ((u16x8*)dst)[i] = o;
  }
}

__global__ void cast_wqkv_k(const float* __restrict__ wq, const float* __restrict__ wk,
                            const float* __restrict__ wv, unsigned short* __restrict__ dst,
                            int n8) {
  int stride = gridDim.x * blockDim.x;
  for (int i = blockIdx.x * blockDim.x + threadIdx.x; i < n8; i += stride) {
    int e = i * 8;
    int row = e >> 11;  // /2048
    const float* s;
    if (row < 2048)      s = wq + e;
    else if (row < 2560) s = wk + (e - 2048 * 2048);
    else                 s = wv + (e - 2560 * 2048);
    f32x4 a = *(const f32x4*)s;
    f32x4 b = *(const f32x4*)(s + 4);
    u16x8 o;
    o[0] = f2bf(a[0]); o[1] = f2bf(a[1]); o[2] = f2bf(a[2]); o[3] = f2bf(a[3]);
    o[4] = f2bf(b[0]); o[5] = f2bf(b[1]); o[6] = f2bf(b[2]); o[7] = f2bf(b[3]);
    ((u16x8*)dst)[i] = o;
  }
}

// ---------------- trig table: trig[t*128 + d] = cos, [t*128+64+d] = sin ------
__global__ void trig_k(float* __restrict__ trig, const int* __restrict__ aps) {
  int i = blockIdx.x * blockDim.x + threadIdx.x;  // < 4096*64
  int t = i >> 6, dp = i & 63;
  float pos = (float)(aps[0] + t);
  float inv = powf(10000.0f, -(float)dp * (1.0f / 64.0f));
  float a = pos * inv;
  float s, c;
  sincosf(a, &s, &c);
  trig[t * 128 + dp] = c;
  trig[t * 128 + 64 + dp] = s;
}

// ---------------- GEMM: C[m,n] = sum_k A[m,k] * W[n,k]  (both bf16, row-major,
// k-contiguous; m97-style 128x128 tile, BK=32, 4 waves, global_load_lds) ------
template <int N, bool F32OUT>
__global__ __launch_bounds__(256) void gemm_bt_k(const unsigned short* __restrict__ A,
                                                 const unsigned short* __restrict__ W,
                                                 void* __restrict__ Cout) {
  __shared__ unsigned short lA[128 * 32];
  __shared__ unsigned short lB[128 * 32];
  const int tid = threadIdx.x;
  const int lane = tid & 63;
  const int wid = tid >> 6;
  const int wm = wid >> 1, wn = wid & 1;
  const int g = lane >> 4, l15 = lane & 15;
  const int bm = blockIdx.y, bn = blockIdx.x;

  f32x4 acc[4][4];
#pragma unroll
  for (int i = 0; i < 4; ++i)
#pragma unroll
    for (int j = 0; j < 4; ++j) acc[i][j] = (f32x4){0.f, 0.f, 0.f, 0.f};

  const int o0 = tid * 16, o1 = tid * 16 + 4096;
  const int r0 = o0 >> 6, c0 = (o0 & 63) >> 1;
  const int r1 = o1 >> 6, c1 = (o1 & 63) >> 1;
  const unsigned short* Ab = A + (size_t)bm * 128 * GK;
  const unsigned short* Wb = W + (size_t)bn * 128 * GK;

  for (int kt = 0; kt < GK; kt += 32) {
    gll16(Ab + (size_t)r0 * GK + kt + c0, (char*)lA + o0);
    gll16(Ab + (size_t)r1 * GK + kt + c1, (char*)lA + o1);
    gll16(Wb + (size_t)r0 * GK + kt + c0, (char*)lB + o0);
    gll16(Wb + (size_t)r1 * GK + kt + c1, (char*)lB + o1);
    asm volatile("s_waitcnt vmcnt(0)" ::: "memory");
    __syncthreads();
    bf16x8 af[4], bfr[4];
#pragma unroll
    for (int f = 0; f < 4; ++f) {
      af[f]  = *(const bf16x8*)&lA[(wm * 64 + f * 16 + l15) * 32 + g * 8];
      bfr[f] = *(const bf16x8*)&lB[(wn * 64 + f * 16 + l15) * 32 + g * 8];
    }
#pragma unroll
    for (int fm = 0; fm < 4; ++fm)
#pragma unroll
      for (int fn = 0; fn < 4; ++fn)
        acc[fm][fn] = __builtin_amdgcn_mfma_f32_16x16x32_bf16(af[fm], bfr[fn], acc[fm][fn], 0, 0, 0);
    __syncthreads();
  }

#pragma unroll
  for (int fm = 0; fm < 4; ++fm)
#pragma unroll
    for (int fn = 0; fn < 4; ++fn) {
      int row = bm * 128 + wm * 64 + fm * 16 + g * 4;
      int col = bn * 128 + wn * 64 + fn * 16 + l15;
#pragma unroll
      for (int r = 0; r < 4; ++r) {
        if (F32OUT)
          ((float*)Cout)[(size_t)(row + r) * N + col] = acc[fm][fn][r];
        else
          ((unsigned short*)Cout)[(size_t)(row + r) * N + col] = f2bf(acc[fm][fn][r]);
      }
    }
}

// ---------------- banded GQA attention -------------------------------------
// grid (kv=4, n=32, b=2), 512 threads (8 waves). Keys jk in [0,256):
// jk<128 -> block n-1, jk>=128 -> block n. Valid: iq+1 <= jk <= iq+128,
// and for n==0 additionally jk>=128.
__global__ __launch_bounds__(512, 2) void attn_k(const unsigned short* __restrict__ qkv,
                                                 const float* __restrict__ trig,
                                                 unsigned short* __restrict__ ob) {
  extern __shared__ char smem[];
  unsigned short* Klds = (unsigned short*)smem;            // [256][128] swizzled
  unsigned short* Vt   = (unsigned short*)(smem + 65536);  // [128][256] swizzled (V^T)
  const int kv = blockIdx.x, n = blockIdx.y, b = blockIdx.z;
  const int tid = threadIdx.x;
  const int lane = tid & 63, w = tid >> 6;
  const int g = lane >> 4, l15 = lane & 15;
  const int koff = DIM_ + kv * HD_;
  const int voff = DIM_ + NKV_ * HD_ + kv * HD_;
  const size_t bbase = (size_t)b * TLEN;

  // ---- stage K with RoPE ----
#pragma unroll
  for (int it = 0; it < 8; ++it) {
    int ch = tid + it * 512;        // 4096 chunks of 8 elems
    int tok = ch >> 4;              // 0..255
    int d0 = (ch & 15) * 8;
    int tk = (n - 1) * 128 + tok;   // absolute sequence pos
    int tkc = tk < 0 ? 0 : tk;
    float gate = tk < 0 ? 0.f : 1.f;
    const unsigned short* rp = qkv + (bbase + tkc) * QKVN + koff;
    u16x8 x1 = *(const u16x8*)(rp + d0);
    u16x8 x2 = *(const u16x8*)(rp + ((d0 + 64) & 127));
    const float* tr = trig + tkc * 128 + (d0 & 63);
    float sgn = (d0 < 64) ? -1.f : 1.f;
    u16x8 outv;
#pragma unroll
    for (int j = 0; j < 8; ++j)
      outv[j] = f2bf(gate * (bf2f(x1[j]) * tr[j] + sgn * bf2f(x2[j]) * tr[64 + j]));
    int byte = (tok * 256 + d0 * 2) ^ swzr(tok);
    *(u16x8*)((char*)Klds + byte) = outv;
  }
  // ---- stage V transposed ----
#pragma unroll
  for (int it = 0; it < 4; ++it) {
    int pc = tid + it * 512;        // 2048 token-pair chunks
    int tok2 = (pc >> 4) * 2;       // even token 0..254
    int d0 = (pc & 15) * 8;
    int tk = (n - 1) * 128 + tok2;
    int tkc = tk < 0 ? 0 : tk;
    float gate = tk < 0 ? 0.f : 1.f;
    u16x8 va = *(const u16x8*)(qkv + (bbase + tkc) * QKVN + voff + d0);
    u16x8 vb = *(const u16x8*)(qkv + (bbase + tkc + 1) * QKVN + voff + d0);
#pragma unroll
    for (int j = 0; j < 8; ++j) {
      unsigned lo = f2bf(gate * bf2f(va[j]));
      unsigned hi = f2bf(gate * bf2f(vb[j]));
      int d = d0 + j;
      int byte = (d * 512 + tok2 * 2) ^ swzr(d);
      *(unsigned*)((char*)Vt + byte) = lo | (hi << 16);
    }
  }
  __syncthreads();

  const int iq = w * 16 + l15;          // this lane's query column
  const int qt = n * 128 + iq;          // sequence position
  const float SCALE = 0.08838834764831845f;

  for (int hh = 0; hh < 4; ++hh) {
    const int h = kv * 4 + hh;
    // Q B-operand fragments with RoPE (direct from global)
    bf16x8 qf[4];
    {
      const unsigned short* rp = qkv + (bbase + qt) * QKVN + h * HD_;
      const float* trq = trig + qt * 128;
#pragma unroll
      for (int ks = 0; ks < 4; ++ks) {
        int d0 = ks * 32 + g * 8;
        u16x8 x1 = *(const u16x8*)(rp + d0);
        u16x8 x2 = *(const u16x8*)(rp + ((d0 + 64) & 127));
        const float* tr = trq + (d0 & 63);
        float sgn = (d0 < 64) ? -1.f : 1.f;
        u16x8 o;
#pragma unroll
        for (int j = 0; j < 8; ++j)
          o[j] = f2bf(bf2f(x1[j]) * tr[j] + sgn * bf2f(x2[j]) * tr[64 + j]);
        qf[ks] = __builtin_bit_cast(bf16x8, o);
      }
    }
    // S^T = K * Q^T : acc[rf] rows jk=rf*16+g*4+r, col iq=l15
    f32x4 acc[16];
#pragma unroll
    for (int rf = 0; rf < 16; ++rf) acc[rf] = (f32x4){0.f, 0.f, 0.f, 0.f};
#pragma unroll
    for (int rf = 0; rf < 16; ++rf) {
      int row = rf * 16 + l15;
      int rowb = row * 256;
#pragma unroll
      for (int ks = 0; ks < 4; ++ks) {
        bf16x8 kf = *(const bf16x8*)((const char*)Klds + ((rowb + ks * 64 + g * 16) ^ swzr(row)));
        acc[rf] = __builtin_amdgcn_mfma_f32_16x16x32_bf16(kf, qf[ks], acc[rf], 0, 0, 0);
      }
    }
    // mask + softmax over jk (rows): per-lane then xor-16/32 lane reduce
    float mx = -1e30f;
#pragma unroll
    for (int rf = 0; rf < 16; ++rf)
#pragma unroll
      for (int r = 0; r < 4; ++r) {
        int jk = rf * 16 + g * 4 + r;
        bool valid = (jk >= iq + 1) && (jk <= iq + 128) && (n > 0 || jk >= 128);
        float s = valid ? acc[rf][r] * SCALE : -1e30f;
        acc[rf][r] = s;
        mx = fmaxf(mx, s);
      }
    mx = fmaxf(mx, __shfl_xor(mx, 16));
    mx = fmaxf(mx, __shfl_xor(mx, 32));
    float sum = 0.f;
#pragma unroll
    for (int rf = 0; rf < 16; ++rf)
#pragma unroll
      for (int r = 0; r < 4; ++r) {
        float e = __expf(acc[rf][r] - mx);
        acc[rf][r] = e;
        sum += e;
      }
    sum += __shfl_xor(sum, 16);
    sum += __shfl_xor(sum, 32);
    // pack P rows into bf16 pairs: pw[rf][rr] = (P[16rf+4g+2rr], P[..+1]) @ col l15
    unsigned pw[16][2];
#pragma unroll
    for (int rf = 0; rf < 16; ++rf) {
      pw[rf][0] = (unsigned)f2bf(acc[rf][0]) | ((unsigned)f2bf(acc[rf][1]) << 16);
      pw[rf][1] = (unsigned)f2bf(acc[rf][2]) | ((unsigned)f2bf(acc[rf][3]) << 16);
    }
    // O^T = V^T * P : PV over 8 k-chunks of 32 keys
    f32x4 oacc[8];
#pragma unroll
    for (int i = 0; i < 8; ++i) oacc[i] = (f32x4){0.f, 0.f, 0.f, 0.f};
#pragma unroll
    for (int c = 0; c < 8; ++c) {
      // exchange C-layout P -> B-operand layout (two-round, 8 shuffles)
      unsigned pb32[4] = {0, 0, 0, 0};
#pragma unroll
      for (int fh = 0; fh < 2; ++fh) {
#pragma unroll
        for (int jj = 0; jj < 4; ++jj) {
          int srcl = l15 + 16 * (2 * (g & 1) + (jj >> 1));
          unsigned t = __shfl(pw[2 * c + fh][jj & 1], srcl, 64);
          if ((g >> 1) == fh) pb32[jj] = t;
        }
      }
      u32x4 pbv = {pb32[0], pb32[1], pb32[2], pb32[3]};
      bf16x8 pb = __builtin_bit_cast(bf16x8, pbv);
#pragma unroll
      for (int fm = 0; fm < 8; ++fm) {
        int row = fm * 16 + l15;
        int rowb = row * 512;
        bf16x8 vf = *(const bf16x8*)((const char*)Vt + ((rowb + c * 64 + g * 16) ^ swzr(row)));
        oacc[fm] = __builtin_amdgcn_mfma_f32_16x16x32_bf16(vf, pb, oacc[fm], 0, 0, 0);
      }
    }
    // epilogue: divide by softmax sum (per-iq == per-lane), write bf16
    float rcp = 1.0f / sum;
    unsigned short* orow = ob + (bbase + qt) * DIM_ + h * HD_;
#pragma unroll
    for (int fm = 0; fm < 8; ++fm) {
      u16x4 o4;
#pragma unroll
      for (int r = 0; r < 4; ++r) o4[r] = f2bf(oacc[fm][r] * rcp);
      *(u16x4*)(orow + fm * 16 + g * 4) = o4;
    }
  }
}

// ---------------------------------------------------------------------------
extern "C" void kernel_launch(void* const* d_in, const int* in_sizes, int n_in,
                              void* d_out, int out_size, void* d_ws, size_t ws_size,
                              hipStream_t stream) {
  const float* x  = (const float*)d_in[0];
  const float* wq = (const float*)d_in[1];
  const float* wk = (const float*)d_in[2];
  const float* wv = (const float*)d_in[3];
  const float* wo = (const float*)d_in[4];
  const int* aps  = (const int*)d_in[5];
  float* y = (float*)d_out;
  char* ws = (char*)d_ws;

  // ws layout (bytes); ob reuses xb (xb dead after GEMM1). Total ~107 MB.
  unsigned short* xb    = (unsigned short*)(ws);                 // 33,554,432
  unsigned short* ob    = (unsigned short*)(ws);                 // reuse
  unsigned short* wqkvb = (unsigned short*)(ws + 33554432);      // 12,582,912
  unsigned short* wob   = (unsigned short*)(ws + 46137344);      //  8,388,608
  unsigned short* qkv   = (unsigned short*)(ws + 54525952);      // 50,331,648
  float* trig           = (float*)(ws + 104857600);              //  2,097,152

  cast_f32_bf16_k<<<2048, 256, 0, stream>>>(x, xb, 8192 * 2048 / 8);
  cast_wqkv_k<<<1024, 256, 0, stream>>>(wq, wk, wv, wqkvb, 3072 * 2048 / 8);
  cast_f32_bf16_k<<<1024, 256, 0, stream>>>(wo, wob, 2048 * 2048 / 8);
  trig_k<<<1024, 256, 0, stream>>>(trig, aps);

  gemm_bt_k<QKVN, false><<<dim3(QKVN / 128, 8192 / 128), 256, 0, stream>>>(xb, wqkvb, (void*)qkv);

  (void)hipFuncSetAttribute((const void*)attn_k,
                            hipFuncAttributeMaxDynamicSharedMemorySize, 131072);
  attn_k<<<dim3(NKV_, TLEN / 128, 2), 512, 131072, stream>>>(qkv, trig, ob);

  gemm_bt_k<DIM_, true><<<dim3(DIM_ / 128, 8192 / 128), 256, 0, stream>>>(ob, wob, (void*)y);
}

// Round 6
// 436.205 us; speedup vs baseline: 1.5160x; 1.5160x over previous
//
#include <hip/hip_runtime.h>

// ---------------------------------------------------------------------------
// GQ sliding-window attention, MI355X (gfx950).
// cast(bf16) -> QKV GEMM (split head-major q/k/v out) -> trig ->
// banded GQA attention (coalesced reads, LDS-transposed O writeback) ->
// output GEMM -> fp32 out.
// Round 5: r5 profile showed attn_k 294us with 7x traffic amplification
// (FETCH 470MB / WRITE 246MB vs ~134MB useful; MfmaUtil 2.3%). Cause:
// token-major interleaved qkv made Q reads 16B-per-6144B-row, and the
// register-layout O^T epilogue made partial-line writes. This round:
// head-major split q/k/v buffers + LDS-staged coalesced O flush.
// ---------------------------------------------------------------------------

typedef __attribute__((ext_vector_type(8))) __bf16 bf16x8;
typedef __attribute__((ext_vector_type(4))) float f32x4;
typedef __attribute__((ext_vector_type(8))) unsigned short u16x8;
typedef __attribute__((ext_vector_type(4))) unsigned short u16x4;
typedef __attribute__((ext_vector_type(4))) unsigned int u32x4;

#define DIM_   2048
#define TLEN   4096
#define NH_    16
#define NKV_   4
#define HD_    128
#define QKVN   3072
#define GK     2048

__device__ __forceinline__ unsigned short f2bf(float f) {
  unsigned u = __builtin_bit_cast(unsigned, f);
  u += 0x7fffu + ((u >> 16) & 1u);
  return (unsigned short)(u >> 16);
}
__device__ __forceinline__ float bf2f(unsigned short h) {
  unsigned u = ((unsigned)h) << 16;
  return __builtin_bit_cast(float, u);
}
__device__ __forceinline__ void gll16(const void* g, void* l) {
  __builtin_amdgcn_global_load_lds(
      (const __attribute__((address_space(1))) unsigned int*)g,
      (__attribute__((address_space(3))) unsigned int*)l, 16, 0, 0);
}
__device__ __forceinline__ int swzr(int row) { return ((row ^ (row >> 3)) & 7) << 4; }

// ---------------- cast kernels ----------------
__global__ void cast_f32_bf16_k(const float* __restrict__ src,
                                unsigned short* __restrict__ dst, int n8) {
  int stride = gridDim.x * blockDim.x;
  for (int i = blockIdx.x * blockDim.x + threadIdx.x; i < n8; i += stride) {
    f32x4 a = ((const f32x4*)src)[2 * i];
    f32x4 b = ((const f32x4*)src)[2 * i + 1];
    u16x8 o;
    o[0] = f2bf(a[0]); o[1] = f2bf(a[1]); o[2] = f2bf(a[2]); o[3] = f2bf(a[3]);
    o[4] = f2bf(b[0]); o[5] = f2bf(b[1]); o[6] = f2bf(b[2]); o[7] = f2bf(b[3]);
    ((u16x8*)dst)[i] = o;
  }
}

__global__ void cast_wqkv_k(const float* __restrict__ wq, const float* __restrict__ wk,
                            const float* __restrict__ wv, unsigned short* __restrict__ dst,
                            int n8) {
  int stride = gridDim.x * blockDim.x;
  for (int i = blockIdx.x * blockDim.x + threadIdx.x; i < n8; i += stride) {
    int e = i * 8;
    int row = e >> 11;
    const float* s;
    if (row < 2048)      s = wq + e;
    else if (row < 2560) s = wk + (e - 2048 * 2048);
    else                 s = wv + (e - 2560 * 2048);
    f32x4 a = *(const f32x4*)s;
    f32x4 b = *(const f32x4*)(s + 4);
    u16x8 o;
    o[0] = f2bf(a[0]); o[1] = f2bf(a[1]); o[2] = f2bf(a[2]); o[3] = f2bf(a[3]);
    o[4] = f2bf(b[0]); o[5] = f2bf(b[1]); o[6] = f2bf(b[2]); o[7] = f2bf(b[3]);
    ((u16x8*)dst)[i] = o;
  }
}

// ---------------- trig table ----------------
__global__ void trig_k(float* __restrict__ trig, const int* __restrict__ aps) {
  int i = blockIdx.x * blockDim.x + threadIdx.x;
  int t = i >> 6, dp = i & 63;
  float pos = (float)(aps[0] + t);
  float inv = powf(10000.0f, -(float)dp * (1.0f / 64.0f));
  float a = pos * inv;
  float s, c;
  sincosf(a, &s, &c);
  trig[t * 128 + dp] = c;
  trig[t * 128 + 64 + dp] = s;
}

// ---------------- QKV GEMM: writes split head-major q/k/v -------------------
__global__ __launch_bounds__(256) void gemm_qkv_k(const unsigned short* __restrict__ A,
                                                  const unsigned short* __restrict__ W,
                                                  unsigned short* __restrict__ qh,
                                                  unsigned short* __restrict__ kb,
                                                  unsigned short* __restrict__ vb) {
  __shared__ unsigned short lA[128 * 32];
  __shared__ unsigned short lB[128 * 32];
  const int tid = threadIdx.x;
  const int lane = tid & 63;
  const int wid = tid >> 6;
  const int wm = wid >> 1, wn = wid & 1;
  const int g = lane >> 4, l15 = lane & 15;
  const int bm = blockIdx.y, bn = blockIdx.x;

  f32x4 acc[4][4];
#pragma unroll
  for (int i = 0; i < 4; ++i)
#pragma unroll
    for (int j = 0; j < 4; ++j) acc[i][j] = (f32x4){0.f, 0.f, 0.f, 0.f};

  const int o0 = tid * 16, o1 = tid * 16 + 4096;
  const int r0 = o0 >> 6, c0 = (o0 & 63) >> 1;
  const int r1 = o1 >> 6, c1 = (o1 & 63) >> 1;
  const unsigned short* Ab = A + (size_t)bm * 128 * GK;
  const unsigned short* Wb = W + (size_t)bn * 128 * GK;

  for (int kt = 0; kt < GK; kt += 32) {
    gll16(Ab + (size_t)r0 * GK + kt + c0, (char*)lA + o0);
    gll16(Ab + (size_t)r1 * GK + kt + c1, (char*)lA + o1);
    gll16(Wb + (size_t)r0 * GK + kt + c0, (char*)lB + o0);
    gll16(Wb + (size_t)r1 * GK + kt + c1, (char*)lB + o1);
    asm volatile("s_waitcnt vmcnt(0)" ::: "memory");
    __syncthreads();
    bf16x8 af[4], bfr[4];
#pragma unroll
    for (int f = 0; f < 4; ++f) {
      af[f]  = *(const bf16x8*)&lA[(wm * 64 + f * 16 + l15) * 32 + g * 8];
      bfr[f] = *(const bf16x8*)&lB[(wn * 64 + f * 16 + l15) * 32 + g * 8];
    }
#pragma unroll
    for (int fm = 0; fm < 4; ++fm)
#pragma unroll
      for (int fn = 0; fn < 4; ++fn)
        acc[fm][fn] = __builtin_amdgcn_mfma_f32_16x16x32_bf16(af[fm], bfr[fn], acc[fm][fn], 0, 0, 0);
    __syncthreads();
  }

  // epilogue: bn tile == one 128-wide head/kv plane (block-uniform branch)
#pragma unroll
  for (int fm = 0; fm < 4; ++fm)
#pragma unroll
    for (int fn = 0; fn < 4; ++fn) {
      int row0 = bm * 128 + wm * 64 + fm * 16 + g * 4;
      int dcol = wn * 64 + fn * 16 + l15;
#pragma unroll
      for (int r = 0; r < 4; ++r) {
        int m = row0 + r;
        int bi = m >> 12, t = m & 4095;
        unsigned short* p;
        if (bn < 16)
          p = qh + (((size_t)bi * NH_ + bn) * TLEN + t) * HD_ + dcol;
        else if (bn < 20)
          p = kb + (((size_t)bi * NKV_ + (bn - 16)) * TLEN + t) * HD_ + dcol;
        else
          p = vb + (((size_t)bi * NKV_ + (bn - 20)) * TLEN + t) * HD_ + dcol;
        *p = f2bf(acc[fm][fn][r]);
      }
    }
}

// ---------------- output GEMM (token-major A, f32 out) ----------------------
template <int N, bool F32OUT>
__global__ __launch_bounds__(256) void gemm_bt_k(const unsigned short* __restrict__ A,
                                                 const unsigned short* __restrict__ W,
                                                 void* __restrict__ Cout) {
  __shared__ unsigned short lA[128 * 32];
  __shared__ unsigned short lB[128 * 32];
  const int tid = threadIdx.x;
  const int lane = tid & 63;
  const int wid = tid >> 6;
  const int wm = wid >> 1, wn = wid & 1;
  const int g = lane >> 4, l15 = lane & 15;
  const int bm = blockIdx.y, bn = blockIdx.x;

  f32x4 acc[4][4];
#pragma unroll
  for (int i = 0; i < 4; ++i)
#pragma unroll
    for (int j = 0; j < 4; ++j) acc[i][j] = (f32x4){0.f, 0.f, 0.f, 0.f};

  const int o0 = tid * 16, o1 = tid * 16 + 4096;
  const int r0 = o0 >> 6, c0 = (o0 & 63) >> 1;
  const int r1 = o1 >> 6, c1 = (o1 & 63) >> 1;
  const unsigned short* Ab = A + (size_t)bm * 128 * GK;
  const unsigned short* Wb = W + (size_t)bn * 128 * GK;

  for (int kt = 0; kt < GK; kt += 32) {
    gll16(Ab + (size_t)r0 * GK + kt + c0, (char*)lA + o0);
    gll16(Ab + (size_t)r1 * GK + kt + c1, (char*)lA + o1);
    gll16(Wb + (size_t)r0 * GK + kt + c0, (char*)lB + o0);
    gll16(Wb + (size_t)r1 * GK + kt + c1, (char*)lB + o1);
    asm volatile("s_waitcnt vmcnt(0)" ::: "memory");
    __syncthreads();
    bf16x8 af[4], bfr[4];
#pragma unroll
    for (int f = 0; f < 4; ++f) {
      af[f]  = *(const bf16x8*)&lA[(wm * 64 + f * 16 + l15) * 32 + g * 8];
      bfr[f] = *(const bf16x8*)&lB[(wn * 64 + f * 16 + l15) * 32 + g * 8];
    }
#pragma unroll
    for (int fm = 0; fm < 4; ++fm)
#pragma unroll
      for (int fn = 0; fn < 4; ++fn)
        acc[fm][fn] = __builtin_amdgcn_mfma_f32_16x16x32_bf16(af[fm], bfr[fn], acc[fm][fn], 0, 0, 0);
    __syncthreads();
  }

#pragma unroll
  for (int fm = 0; fm < 4; ++fm)
#pragma unroll
    for (int fn = 0; fn < 4; ++fn) {
      int row = bm * 128 + wm * 64 + fm * 16 + g * 4;
      int col = bn * 128 + wn * 64 + fn * 16 + l15;
#pragma unroll
      for (int r = 0; r < 4; ++r) {
        if (F32OUT)
          ((float*)Cout)[(size_t)(row + r) * N + col] = acc[fm][fn][r];
        else
          ((unsigned short*)Cout)[(size_t)(row + r) * N + col] = f2bf(acc[fm][fn][r]);
      }
    }
}

// ---------------- banded GQA attention -------------------------------------
// grid (kv=4, n=32, b=2), 512 threads (8 waves).
// LDS: K [256][128] swz (64K) | V^T [128][256] swz (64K) | Ot [64][136] (17K)
__global__ __launch_bounds__(512, 2) void attn_k(const unsigned short* __restrict__ qh,
                                                 const unsigned short* __restrict__ kbuf,
                                                 const unsigned short* __restrict__ vbuf,
                                                 const float* __restrict__ trig,
                                                 unsigned short* __restrict__ ob) {
  extern __shared__ char smem[];
  unsigned short* Klds = (unsigned short*)smem;
  unsigned short* Vt   = (unsigned short*)(smem + 65536);
  unsigned short* Ot   = (unsigned short*)(smem + 131072);
  const int kv = blockIdx.x, n = blockIdx.y, b = blockIdx.z;
  const int tid = threadIdx.x;
  const int lane = tid & 63, w = tid >> 6;
  const int g = lane >> 4, l15 = lane & 15;
  const size_t bbase = (size_t)b * TLEN;
  const unsigned short* kbase = kbuf + ((size_t)b * NKV_ + kv) * TLEN * HD_;
  const unsigned short* vbase = vbuf + ((size_t)b * NKV_ + kv) * TLEN * HD_;

  // ---- stage K with RoPE (rows 256B contiguous, fully coalesced) ----
#pragma unroll
  for (int it = 0; it < 8; ++it) {
    int ch = tid + it * 512;
    int tok = ch >> 4;
    int d0 = (ch & 15) * 8;
    int tk = (n - 1) * 128 + tok;
    int tkc = tk < 0 ? 0 : tk;
    float gate = tk < 0 ? 0.f : 1.f;
    const unsigned short* rp = kbase + (size_t)tkc * HD_;
    u16x8 x1 = *(const u16x8*)(rp + d0);
    u16x8 x2 = *(const u16x8*)(rp + ((d0 + 64) & 127));
    const float* tr = trig + tkc * 128 + (d0 & 63);
    float sgn = (d0 < 64) ? -1.f : 1.f;
    u16x8 outv;
#pragma unroll
    for (int j = 0; j < 8; ++j)
      outv[j] = f2bf(gate * (bf2f(x1[j]) * tr[j] + sgn * bf2f(x2[j]) * tr[64 + j]));
    int byte = (tok * 256 + d0 * 2) ^ swzr(tok);
    *(u16x8*)((char*)Klds + byte) = outv;
  }
  // ---- stage V transposed ----
#pragma unroll
  for (int it = 0; it < 4; ++it) {
    int pc = tid + it * 512;
    int tok2 = (pc >> 4) * 2;
    int d0 = (pc & 15) * 8;
    int tk = (n - 1) * 128 + tok2;
    int tkc = tk < 0 ? 0 : tk;
    float gate = tk < 0 ? 0.f : 1.f;
    u16x8 va = *(const u16x8*)(vbase + (size_t)tkc * HD_ + d0);
    u16x8 vb2 = *(const u16x8*)(vbase + (size_t)(tkc + 1) * HD_ + d0);
#pragma unroll
    for (int j = 0; j < 8; ++j) {
      unsigned lo = f2bf(gate * bf2f(va[j]));
      unsigned hi = f2bf(gate * bf2f(vb2[j]));
      int d = d0 + j;
      int byte = (d * 512 + tok2 * 2) ^ swzr(d);
      *(unsigned*)((char*)Vt + byte) = lo | (hi << 16);
    }
  }
  __syncthreads();

  const int iq = w * 16 + l15;
  const int qt = n * 128 + iq;
  const float SCALE = 0.08838834764831845f;

  for (int hh = 0; hh < 4; ++hh) {
    const int h = kv * 4 + hh;
    // Q fragments with RoPE (head-major rows: 256B apart, line-dense)
    bf16x8 qf[4];
    {
      const unsigned short* rp = qh + (((size_t)b * NH_ + h) * TLEN + qt) * HD_;
      const float* trq = trig + qt * 128;
#pragma unroll
      for (int ks = 0; ks < 4; ++ks) {
        int d0 = ks * 32 + g * 8;
        u16x8 x1 = *(const u16x8*)(rp + d0);
        u16x8 x2 = *(const u16x8*)(rp + ((d0 + 64) & 127));
        const float* tr = trq + (d0 & 63);
        float sgn = (d0 < 64) ? -1.f : 1.f;
        u16x8 o;
#pragma unroll
        for (int j = 0; j < 8; ++j)
          o[j] = f2bf(bf2f(x1[j]) * tr[j] + sgn * bf2f(x2[j]) * tr[64 + j]);
        qf[ks] = __builtin_bit_cast(bf16x8, o);
      }
    }
    // S^T = K * Q^T
    f32x4 acc[16];
#pragma unroll
    for (int rf = 0; rf < 16; ++rf) acc[rf] = (f32x4){0.f, 0.f, 0.f, 0.f};
#pragma unroll
    for (int rf = 0; rf < 16; ++rf) {
      int row = rf * 16 + l15;
      int rowb = row * 256;
#pragma unroll
      for (int ks = 0; ks < 4; ++ks) {
        bf16x8 kf = *(const bf16x8*)((const char*)Klds + ((rowb + ks * 64 + g * 16) ^ swzr(row)));
        acc[rf] = __builtin_amdgcn_mfma_f32_16x16x32_bf16(kf, qf[ks], acc[rf], 0, 0, 0);
      }
    }
    // mask + softmax over jk
    float mx = -1e30f;
#pragma unroll
    for (int rf = 0; rf < 16; ++rf)
#pragma unroll
      for (int r = 0; r < 4; ++r) {
        int jk = rf * 16 + g * 4 + r;
        bool valid = (jk >= iq + 1) && (jk <= iq + 128) && (n > 0 || jk >= 128);
        float s = valid ? acc[rf][r] * SCALE : -1e30f;
        acc[rf][r] = s;
        mx = fmaxf(mx, s);
      }
    mx = fmaxf(mx, __shfl_xor(mx, 16));
    mx = fmaxf(mx, __shfl_xor(mx, 32));
    float sum = 0.f;
#pragma unroll
    for (int rf = 0; rf < 16; ++rf)
#pragma unroll
      for (int r = 0; r < 4; ++r) {
        float e = __expf(acc[rf][r] - mx);
        acc[rf][r] = e;
        sum += e;
      }
    sum += __shfl_xor(sum, 16);
    sum += __shfl_xor(sum, 32);
    unsigned pw[16][2];
#pragma unroll
    for (int rf = 0; rf < 16; ++rf) {
      pw[rf][0] = (unsigned)f2bf(acc[rf][0]) | ((unsigned)f2bf(acc[rf][1]) << 16);
      pw[rf][1] = (unsigned)f2bf(acc[rf][2]) | ((unsigned)f2bf(acc[rf][3]) << 16);
    }
    // O^T = V^T * P
    f32x4 oacc[8];
#pragma unroll
    for (int i = 0; i < 8; ++i) oacc[i] = (f32x4){0.f, 0.f, 0.f, 0.f};
#pragma unroll
    for (int c = 0; c < 8; ++c) {
      unsigned pb32[4] = {0, 0, 0, 0};
#pragma unroll
      for (int fh = 0; fh < 2; ++fh) {
#pragma unroll
        for (int jj = 0; jj < 4; ++jj) {
          int srcl = l15 + 16 * (2 * (g & 1) + (jj >> 1));
          unsigned t = __shfl(pw[2 * c + fh][jj & 1], srcl, 64);
          if ((g >> 1) == fh) pb32[jj] = t;
        }
      }
      u32x4 pbv = {pb32[0], pb32[1], pb32[2], pb32[3]};
      bf16x8 pb = __builtin_bit_cast(bf16x8, pbv);
#pragma unroll
      for (int fm = 0; fm < 8; ++fm) {
        int row = fm * 16 + l15;
        int rowb = row * 512;
        bf16x8 vf = *(const bf16x8*)((const char*)Vt + ((rowb + c * 64 + g * 16) ^ swzr(row)));
        oacc[fm] = __builtin_amdgcn_mfma_f32_16x16x32_bf16(vf, pb, oacc[fm], 0, 0, 0);
      }
    }
    // epilogue: LDS-transpose O then coalesced full-line flush (2 phases of
    // 64 tokens; Ot stride 136 elems keeps LDS ops <=2-way conflicted)
    float rcp = 1.0f / sum;
#pragma unroll
    for (int ph = 0; ph < 2; ++ph) {
      __syncthreads();  // Ot free (prev flush / prev head done)
      if ((w >> 2) == ph) {
        int tq = (w & 3) * 16 + l15;
        unsigned short* orow = Ot + tq * 136;
#pragma unroll
        for (int fm = 0; fm < 8; ++fm) {
          u16x4 o4;
#pragma unroll
          for (int r = 0; r < 4; ++r) o4[r] = f2bf(oacc[fm][r] * rcp);
          *(u16x4*)(orow + fm * 16 + g * 4) = o4;
        }
      }
      __syncthreads();
      int t2 = tid >> 3, sub = tid & 7;
      const unsigned short* lp = Ot + t2 * 136 + sub * 16;
      u16x8 v0 = *(const u16x8*)lp;
      u16x8 v1 = *(const u16x8*)(lp + 8);
      unsigned short* gp = ob + (bbase + (size_t)n * 128 + ph * 64 + t2) * DIM_ + h * HD_ + sub * 16;
      *(u16x8*)gp = v0;
      *(u16x8*)(gp + 8) = v1;
    }
  }
}

// ---------------------------------------------------------------------------
extern "C" void kernel_launch(void* const* d_in, const int* in_sizes, int n_in,
                              void* d_out, int out_size, void* d_ws, size_t ws_size,
                              hipStream_t stream) {
  const float* x  = (const float*)d_in[0];
  const float* wq = (const float*)d_in[1];
  const float* wk = (const float*)d_in[2];
  const float* wv = (const float*)d_in[3];
  const float* wo = (const float*)d_in[4];
  const int* aps  = (const int*)d_in[5];
  float* y = (float*)d_out;
  char* ws = (char*)d_ws;

  // ws layout (bytes); ob aliases xb (dead after GEMM1). Total ~102 MB.
  unsigned short* xb    = (unsigned short*)(ws);                 // 33,554,432
  unsigned short* ob    = (unsigned short*)(ws);                 // reuse
  unsigned short* wqkvb = (unsigned short*)(ws + 33554432);      // 12,582,912
  unsigned short* wob   = (unsigned short*)(ws + 46137344);      //  8,388,608
  unsigned short* qh    = (unsigned short*)(ws + 54525952);      // 33,554,432
  unsigned short* kb    = (unsigned short*)(ws + 88080384);      //  8,388,608
  unsigned short* vb    = (unsigned short*)(ws + 96468992);      //  8,388,608
  float* trig           = (float*)(ws + 104857600);              //  2,097,152

  cast_f32_bf16_k<<<2048, 256, 0, stream>>>(x, xb, 8192 * 2048 / 8);
  cast_wqkv_k<<<1024, 256, 0, stream>>>(wq, wk, wv, wqkvb, 3072 * 2048 / 8);
  cast_f32_bf16_k<<<1024, 256, 0, stream>>>(wo, wob, 2048 * 2048 / 8);
  trig_k<<<1024, 256, 0, stream>>>(trig, aps);

  gemm_qkv_k<<<dim3(QKVN / 128, 8192 / 128), 256, 0, stream>>>(xb, wqkvb, qh, kb, vb);

  (void)hipFuncSetAttribute((const void*)attn_k,
                            hipFuncAttributeMaxDynamicSharedMemorySize, 148480);
  attn_k<<<dim3(NKV_, TLEN / 128, 2), 512, 148480, stream>>>(qh, kb, vb, trig, ob);

  gemm_bt_k<DIM_, true><<<dim3(DIM_ / 128, 8192 / 128), 256, 0, stream>>>(ob, wob, (void*)y);
}